// Round 9
// baseline (1657.081 us; speedup 1.0000x reference)
//
#include <hip/hip_runtime.h>
#include <hip/hip_bf16.h>

typedef __bf16 bf16x8 __attribute__((ext_vector_type(8)));
typedef __bf16 bf16x4 __attribute__((ext_vector_type(4)));
typedef float  f32x4  __attribute__((ext_vector_type(4)));

#define MFMA16(a, b, c) __builtin_amdgcn_mfma_f32_16x16x32_bf16((a), (b), (c), 0, 0, 0)
#define SB() __builtin_amdgcn_sched_barrier(0)

// async global->LDS copy, 16B per lane; LDS dest = wave-uniform base + lane*16
__device__ __forceinline__ void async_copy16(const void* g, void* l) {
    __builtin_amdgcn_global_load_lds(
        (const __attribute__((address_space(1))) void*)g,
        (__attribute__((address_space(3))) void*)l, 16, 0, 0);
}

// ---------------------------------------------------------------------------
__global__ void zero_stats_kernel(float* s) { s[threadIdx.x] = 0.0f; }

// ---------------------------------------------------------------------------
// Fused: GN1 stats (per-group sum/sumsq over f32 x) + cast x -> bf16 copy xb.
__global__ __launch_bounds__(256) void caststats_kernel(
    const f32x4* __restrict__ x, bf16x4* __restrict__ xb,
    float* __restrict__ stats, int nvec)
{
    int nth = gridDim.x * blockDim.x;
    int gt = blockIdx.x * blockDim.x + threadIdx.x;
    float s = 0.f, ss = 0.f;
    for (int f = gt; f < nvec; f += nth) {
        f32x4 v = x[f];
        s  += v[0] + v[1] + v[2] + v[3];
        ss += v[0] * v[0] + v[1] * v[1] + v[2] * v[2] + v[3] * v[3];
        bf16x4 b;
        b[0] = (__bf16)v[0]; b[1] = (__bf16)v[1];
        b[2] = (__bf16)v[2]; b[3] = (__bf16)v[3];
        xb[f] = b;
    }
    __shared__ float ls[16];
    if (threadIdx.x < 16) ls[threadIdx.x] = 0.f;
    __syncthreads();
    int g = gt & 7;
    atomicAdd(&ls[2 * g], s);
    atomicAdd(&ls[2 * g + 1], ss);
    __syncthreads();
    if (threadIdx.x < 16) atomicAdd(&stats[threadIdx.x], ls[threadIdx.x]);
}

// ---------------------------------------------------------------------------
// Fold GN1 affine into W1 (bf16 B-frag pack), pack Wskip, conv1 bias, feat.
// bp1 index: [k][ct][lane][j] (27*4*64*8)
__global__ __launch_bounds__(256) void fold1_kernel(
    const float* __restrict__ W1, const float* __restrict__ gamma1,
    const float* __restrict__ beta1, const float* __restrict__ Wskip,
    const float* __restrict__ stats1,
    __bf16* __restrict__ bp1, __bf16* __restrict__ bps,
    float* __restrict__ bias1,
    const int* __restrict__ feat, int* __restrict__ feat_out, float inv_n)
{
    int b = blockIdx.x, t = threadIdx.x;
    if (b < 216) {
        int e = b * 256 + t;
        int j = e & 7, lane = (e >> 3) & 63, ct = (e >> 9) & 3, k = e >> 11;
        int ci = ((lane >> 4) << 3) + j;
        int co = (ct << 4) + (lane & 15);
        int g = ci >> 2;
        float mean = stats1[2 * g] * inv_n;
        float var  = stats1[2 * g + 1] * inv_n - mean * mean;
        float r = rsqrtf(var + 1e-5f);
        float a = gamma1[ci] * r;
        bp1[e] = (__bf16)(a * W1[k * 2048 + ci * 64 + co]);
    } else if (b == 216) {
        if (t < 64) {
            float sum = 0.0f;
            for (int ci = 0; ci < 32; ++ci) {
                int g = ci >> 2;
                float mean = stats1[2 * g] * inv_n;
                float var  = stats1[2 * g + 1] * inv_n - mean * mean;
                float r = rsqrtf(var + 1e-5f);
                float a = gamma1[ci] * r;
                float bb = beta1[ci] - mean * a;
                float ws = 0.0f;
                for (int k = 0; k < 27; ++k) ws += W1[k * 2048 + ci * 64 + t];
                sum += bb * ws;
            }
            bias1[t] = sum;
        } else if (t == 64) {
            feat_out[0] = feat[0];
        }
    } else {
        int e = (b - 217) * 256 + t;
        int j = e & 7, lane = (e >> 3) & 63, ct = e >> 9;
        int ci = ((lane >> 4) << 3) + j;
        int co = (ct << 4) + (lane & 15);
        bps[e] = (__bf16)Wskip[ci * 64 + co];
    }
}

// ---------------------------------------------------------------------------
// Fold GN2 into W2.  bp2 index: [k][hf][ct][lane][j]  (27*2*4*64*8)
__global__ __launch_bounds__(256) void fold2_kernel(
    const float* __restrict__ W2, const float* __restrict__ gamma2,
    const float* __restrict__ beta2, const float* __restrict__ stats2,
    __bf16* __restrict__ bp2, float* __restrict__ bias2, float inv_n)
{
    int b = blockIdx.x, t = threadIdx.x;
    if (b < 432) {
        int e = b * 256 + t;
        int j = e & 7, lane = (e >> 3) & 63, ct = (e >> 9) & 3, hf = (e >> 11) & 1, k = e >> 12;
        int ci = (hf << 5) + ((lane >> 4) << 3) + j;
        int co = (ct << 4) + (lane & 15);
        int g = ci >> 3;
        float mean = stats2[2 * g] * inv_n;
        float var  = stats2[2 * g + 1] * inv_n - mean * mean;
        float r = rsqrtf(var + 1e-5f);
        float a = gamma2[ci] * r;
        bp2[e] = (__bf16)(a * W2[k * 4096 + ci * 64 + co]);
    } else if (t < 64) {
        float sum = 0.0f;
        for (int ci = 0; ci < 64; ++ci) {
            int g = ci >> 3;
            float mean = stats2[2 * g] * inv_n;
            float var  = stats2[2 * g + 1] * inv_n - mean * mean;
            float r = rsqrtf(var + 1e-5f);
            float a = gamma2[ci] * r;
            float bb = beta2[ci] - mean * a;
            float ws = 0.0f;
            for (int k = 0; k < 27; ++k) ws += W2[k * 4096 + ci * 64 + t];
            sum += bb * ws;
        }
        bias2[t] = sum;
    }
}

// ---------------------------------------------------------------------------
// conv1: double-buffered B in LDS (2 x 3-tap chunks), counted-vmcnt chunk
// boundaries (vmcnt never 0 in steady state), gathers issued 2 chunks ahead.
__global__ __launch_bounds__(256, 4) void conv1_kernel(
    const __bf16* __restrict__ xb, const int* __restrict__ nbr,
    const __bf16* __restrict__ bp1, const float* __restrict__ bias1,
    __bf16* __restrict__ h, float* __restrict__ stats2, int nTiles)
{
    __shared__ int sidx[4][864];
    __shared__ __align__(16) __bf16 Bs[2][3 * 2048];   // 2 x 12 KB
    __shared__ float ls[16];
    const int wav = threadIdx.x >> 6, lane = threadIdx.x & 63;
    const int unit = blockIdx.x * 4 + wav;
    const int t0 = unit * 2;
    const bool act0 = t0 < nTiles, act1 = t0 + 1 < nTiles;
    if (threadIdx.x < 16) ls[threadIdx.x] = 0.f;
    const int lm = lane & 15, q = lane >> 4;

    {
        const int tc = act0 ? t0 : 0;
        const int* gi = nbr + (size_t)tc * 432;
        const int cnt = (act0 && act1) ? 864 : 432;
        for (int i = lane; i < 864; i += 64) sidx[wav][i] = (i < cnt) ? gi[i] : 0;
    }
    const int* s0p = &sidx[wav][lm * 27];
    const int* s1p = &sidx[wav][432 + lm * 27];
    const bf16x8* Bv0 = (const bf16x8*)Bs[0];
    const bf16x8* Bv1 = (const bf16x8*)Bs[1];

    f32x4 c[8] = {};
    bf16x8 P0[6], P1[6];                 // 2 chunks of gather data in regs

#define STG1(CNK, BUF) { const __bf16* gs = bp1 + (size_t)(CNK) * 3 * 2048; \
    _Pragma("unroll") for (int i = 0; i < 3; ++i) { int part = wav * 3 + i; \
        async_copy16(gs + part * 512 + lane * 8, &Bs[BUF][part * 512]); } }
#define GT1(T, S) { \
    P0[S] = *(const bf16x8*)(xb + (size_t)s0p[T] * 32 + q * 8); \
    P1[S] = *(const bf16x8*)(xb + (size_t)s1p[T] * 32 + q * 8); }
#define TAP1(T, S, BSEL) { const bf16x8* Bv = (BSEL) ? Bv1 : Bv0; \
    const int bb = ((T) % 3) * 256 + lane; \
    bf16x8 b0 = Bv[bb], b1 = Bv[bb + 64], b2 = Bv[bb + 128], b3 = Bv[bb + 192]; \
    c[0] = MFMA16(P0[S], b0, c[0]); c[1] = MFMA16(P0[S], b1, c[1]); \
    c[2] = MFMA16(P0[S], b2, c[2]); c[3] = MFMA16(P0[S], b3, c[3]); \
    c[4] = MFMA16(P1[S], b0, c[4]); c[5] = MFMA16(P1[S], b1, c[5]); \
    c[6] = MFMA16(P1[S], b2, c[6]); c[7] = MFMA16(P1[S], b3, c[7]); }
#define CHK1(C) { \
    STG1((C) + 1, ((C) + 1) & 1); SB(); \
    TAP1(3*(C)+0, (3*(C)+0) % 6, (C) & 1); \
    TAP1(3*(C)+1, (3*(C)+1) % 6, (C) & 1); \
    TAP1(3*(C)+2, (3*(C)+2) % 6, (C) & 1); \
    GT1(3*(C)+6, (3*(C)+6) % 6); \
    GT1(3*(C)+7, (3*(C)+7) % 6); \
    GT1(3*(C)+8, (3*(C)+8) % 6); \
    SB(); \
    asm volatile("s_waitcnt vmcnt(6) lgkmcnt(0)" ::: "memory"); \
    __builtin_amdgcn_s_barrier(); SB(); }

    // prologue: stage chunk0, gather chunks 0+1 (12 loads after the stage)
    STG1(0, 0); SB();
    GT1(0, 0) GT1(1, 1) GT1(2, 2) GT1(3, 3) GT1(4, 4) GT1(5, 5)
    SB();
    asm volatile("s_waitcnt vmcnt(12)" ::: "memory");   // stage0 (oldest) done
    __builtin_amdgcn_s_barrier(); SB();

    CHK1(0) CHK1(1) CHK1(2) CHK1(3) CHK1(4) CHK1(5) CHK1(6)
    // chunk 7: stage chunk 8, no more gathers -> must drain stage fully
    STG1(8, 0); SB();
    TAP1(21, 3, 1) TAP1(22, 4, 1) TAP1(23, 5, 1)
    SB();
    asm volatile("s_waitcnt vmcnt(0) lgkmcnt(0)" ::: "memory");
    __builtin_amdgcn_s_barrier(); SB();
    // chunk 8: compute only
    TAP1(24, 0, 0) TAP1(25, 1, 0) TAP1(26, 2, 0)
#undef CHK1
#undef TAP1
#undef GT1
#undef STG1

    if (act0) {
        // C/D layout: col = lane&15 (cout), row = q*4 + r (voxel)
#define EPI1(CI, CT, V0) { \
        float bsv = bias1[(CT) * 16 + lm]; \
        float ps = 0.f, pss = 0.f; \
        _Pragma("unroll") \
        for (int r = 0; r < 4; ++r) { \
            float val = c[CI][r] + bsv; \
            val = val / (1.0f + __expf(-val)); \
            h[(size_t)((V0) + q * 4 + r) * 64 + (CT) * 16 + lm] = (__bf16)val; \
            ps += val; pss += val * val; } \
        int g2 = (CT) * 2 + (lm >> 3); \
        atomicAdd(&ls[2 * g2], ps); atomicAdd(&ls[2 * g2 + 1], pss); }
        const int v0 = t0 * 16;
        EPI1(0, 0, v0) EPI1(1, 1, v0) EPI1(2, 2, v0) EPI1(3, 3, v0)
        if (act1) {
            const int v1 = v0 + 16;
            EPI1(4, 0, v1) EPI1(5, 1, v1) EPI1(6, 2, v1) EPI1(7, 3, v1)
        }
#undef EPI1
    }
    __syncthreads();
    if (threadIdx.x < 16) atomicAdd(&stats2[threadIdx.x], ls[threadIdx.x]);
}

// ---------------------------------------------------------------------------
// conv2 + skip: same counted-vmcnt double-buffer structure; 63 KB LDS ->
// 2 blocks/CU, compensated by 2-chunk gather lead + no vmcnt drains.
__global__ __launch_bounds__(256, 2) void conv2_kernel(
    const __bf16* __restrict__ h, const __bf16* __restrict__ xb,
    const int* __restrict__ nbr,
    const __bf16* __restrict__ bp2, const __bf16* __restrict__ bps,
    const float* __restrict__ bias2, const float* __restrict__ bskip,
    float* __restrict__ out, int nTiles)
{
    __shared__ int sidx[4][864];
    __shared__ __align__(16) __bf16 Bs[2][3 * 4096];   // 2 x 24 KB
    const int wav = threadIdx.x >> 6, lane = threadIdx.x & 63;
    const int unit = blockIdx.x * 4 + wav;
    const int t0 = unit * 2;
    const bool act0 = t0 < nTiles, act1 = t0 + 1 < nTiles;
    const int lm = lane & 15, q = lane >> 4;

    {
        const int tc = act0 ? t0 : 0;
        const int* gi = nbr + (size_t)tc * 432;
        const int cnt = (act0 && act1) ? 864 : 432;
        for (int i = lane; i < 864; i += 64) sidx[wav][i] = (i < cnt) ? gi[i] : 0;
    }
    const int* s0p = &sidx[wav][lm * 27];
    const int* s1p = &sidx[wav][432 + lm * 27];
    const bf16x8* Bv0 = (const bf16x8*)Bs[0];
    const bf16x8* Bv1 = (const bf16x8*)Bs[1];

    f32x4 c[8] = {};
    bf16x8 P0l[6], P0h[6], P1l[6], P1h[6];   // 2 chunks of gathers (96 VGPR)

#define STG2(CNK, BUF) { const __bf16* gs = bp2 + (size_t)(CNK) * 3 * 4096; \
    _Pragma("unroll") for (int i = 0; i < 6; ++i) { int part = wav * 6 + i; \
        async_copy16(gs + part * 512 + lane * 8, &Bs[BUF][part * 512]); } }
#define GT2(T, S) { const __bf16* p0 = h + (size_t)s0p[T] * 64; \
    const __bf16* p1 = h + (size_t)s1p[T] * 64; \
    P0l[S] = *(const bf16x8*)(p0 + q * 8); \
    P0h[S] = *(const bf16x8*)(p0 + 32 + q * 8); \
    P1l[S] = *(const bf16x8*)(p1 + q * 8); \
    P1h[S] = *(const bf16x8*)(p1 + 32 + q * 8); }
#define TAP2(T, S, BSEL) { const bf16x8* Bv = (BSEL) ? Bv1 : Bv0; \
    const int bb = ((T) % 3) * 512 + lane; \
    bf16x8 b0 = Bv[bb], b1 = Bv[bb + 64], b2 = Bv[bb + 128], b3 = Bv[bb + 192]; \
    c[0] = MFMA16(P0l[S], b0, c[0]); c[1] = MFMA16(P0l[S], b1, c[1]); \
    c[2] = MFMA16(P0l[S], b2, c[2]); c[3] = MFMA16(P0l[S], b3, c[3]); \
    c[4] = MFMA16(P1l[S], b0, c[4]); c[5] = MFMA16(P1l[S], b1, c[5]); \
    c[6] = MFMA16(P1l[S], b2, c[6]); c[7] = MFMA16(P1l[S], b3, c[7]); \
    bf16x8 b4 = Bv[bb + 256], b5 = Bv[bb + 320], b6 = Bv[bb + 384], b7 = Bv[bb + 448]; \
    c[0] = MFMA16(P0h[S], b4, c[0]); c[1] = MFMA16(P0h[S], b5, c[1]); \
    c[2] = MFMA16(P0h[S], b6, c[2]); c[3] = MFMA16(P0h[S], b7, c[3]); \
    c[4] = MFMA16(P1h[S], b4, c[4]); c[5] = MFMA16(P1h[S], b5, c[5]); \
    c[6] = MFMA16(P1h[S], b6, c[6]); c[7] = MFMA16(P1h[S], b7, c[7]); }
#define CHK2(C) { \
    STG2((C) + 1, ((C) + 1) & 1); SB(); \
    TAP2(3*(C)+0, (3*(C)+0) % 6, (C) & 1); \
    TAP2(3*(C)+1, (3*(C)+1) % 6, (C) & 1); \
    TAP2(3*(C)+2, (3*(C)+2) % 6, (C) & 1); \
    GT2(3*(C)+6, (3*(C)+6) % 6); \
    GT2(3*(C)+7, (3*(C)+7) % 6); \
    GT2(3*(C)+8, (3*(C)+8) % 6); \
    SB(); \
    asm volatile("s_waitcnt vmcnt(12) lgkmcnt(0)" ::: "memory"); \
    __builtin_amdgcn_s_barrier(); SB(); }

    // prologue: stage chunk0, gather chunks 0+1 (24 loads after the stage)
    STG2(0, 0); SB();
    GT2(0, 0) GT2(1, 1) GT2(2, 2) GT2(3, 3) GT2(4, 4) GT2(5, 5)
    SB();
    asm volatile("s_waitcnt vmcnt(24)" ::: "memory");   // stage0 (oldest) done
    __builtin_amdgcn_s_barrier(); SB();

    CHK2(0) CHK2(1) CHK2(2) CHK2(3) CHK2(4) CHK2(5) CHK2(6)
    // chunk 7: stage chunk 8, no more gathers -> drain stage fully
    STG2(8, 0); SB();
    TAP2(21, 3, 1) TAP2(22, 4, 1) TAP2(23, 5, 1)
    SB();
    asm volatile("s_waitcnt vmcnt(0) lgkmcnt(0)" ::: "memory");
    __builtin_amdgcn_s_barrier(); SB();
    // chunk 8: compute only
    TAP2(24, 0, 0) TAP2(25, 1, 0) TAP2(26, 2, 0)
#undef CHK2
#undef TAP2
#undef GT2
#undef STG2

    if (!act0) return;
    // skip 1x1 conv after the K-loop (short accumulator live range)
    f32x4 s[8] = {};
    {
        const bf16x8* bsp = (const bf16x8*)bps;
        bf16x8 ax0 = *(const bf16x8*)(xb + ((size_t)t0 * 16 + lm) * 32 + q * 8);
        bf16x8 w0 = bsp[lane], w1 = bsp[64 + lane], w2 = bsp[128 + lane], w3 = bsp[192 + lane];
        s[0] = MFMA16(ax0, w0, s[0]);
        s[1] = MFMA16(ax0, w1, s[1]);
        s[2] = MFMA16(ax0, w2, s[2]);
        s[3] = MFMA16(ax0, w3, s[3]);
        if (act1) {
            bf16x8 ax1 = *(const bf16x8*)(xb + ((size_t)t0 * 16 + 16 + lm) * 32 + q * 8);
            s[4] = MFMA16(ax1, w0, s[4]);
            s[5] = MFMA16(ax1, w1, s[5]);
            s[6] = MFMA16(ax1, w2, s[6]);
            s[7] = MFMA16(ax1, w3, s[7]);
        }
    }
#define EPI2(CI, CT, V0) { \
        int co = (CT) * 16 + lm; \
        float b2v = bias2[co]; \
        float bsk = bskip[co]; \
        _Pragma("unroll") \
        for (int r = 0; r < 4; ++r) { \
            float val = c[CI][r] + b2v; \
            val = val / (1.0f + __expf(-val)); \
            val += s[CI][r] + bsk; \
            out[(size_t)((V0) + q * 4 + r) * 64 + co] = val; } }
    const int v0 = t0 * 16;
    EPI2(0, 0, v0) EPI2(1, 1, v0) EPI2(2, 2, v0) EPI2(3, 3, v0)
    if (act1) {
        const int v1 = v0 + 16;
        EPI2(4, 0, v1) EPI2(5, 1, v1) EPI2(6, 2, v1) EPI2(7, 3, v1)
    }
#undef EPI2
}

// ---------------------------------------------------------------------------
extern "C" void kernel_launch(void* const* d_in, const int* in_sizes, int n_in,
                              void* d_out, int out_size, void* d_ws, size_t ws_size,
                              hipStream_t stream)
{
    (void)n_in; (void)out_size; (void)ws_size;
    const float* x      = (const float*)d_in[0];
    const int*   nbr    = (const int*)d_in[1];
    const float* gamma1 = (const float*)d_in[2];
    const float* beta1  = (const float*)d_in[3];
    const float* W1     = (const float*)d_in[4];
    const float* gamma2 = (const float*)d_in[5];
    const float* beta2  = (const float*)d_in[6];
    const float* W2     = (const float*)d_in[7];
    const float* Wskip  = (const float*)d_in[8];
    const float* bskip  = (const float*)d_in[9];
    const int*   feat   = (const int*)d_in[10];
    const int N = in_sizes[0] / 32;

    char* ws = (char*)d_ws;
    float* stats1 = (float*)ws;                 // 16 floats
    float* stats2 = stats1 + 16;                // 16 floats
    float* bias1  = stats1 + 32;                // 64 floats
    float* bias2  = stats1 + 96;                // 64 floats
    __bf16* bp1 = (__bf16*)(ws + (1 << 10));    // 55296 elems
    __bf16* bps = (__bf16*)(ws + (1 << 17));    // 2048 elems
    __bf16* bp2 = (__bf16*)(ws + 144 * 1024);   // 110592 elems
    __bf16* xb  = (__bf16*)(ws + (1 << 20));    // N*32 bf16 = 32 MB
    __bf16* h   = (__bf16*)(ws + (size_t)34 * (1 << 20)); // N*64 bf16 = 64 MB
    float* outb = (float*)d_out;

    const int nTiles = (N + 15) / 16;           // 31250
    const int units = (nTiles + 1) / 2;         // 15625
    const int convBlocks = (units + 3) / 4;     // 3907

    hipLaunchKernelGGL(zero_stats_kernel, dim3(1), dim3(32), 0, stream, stats1);
    hipLaunchKernelGGL(caststats_kernel, dim3(2048), dim3(256), 0, stream,
                       (const f32x4*)x, (bf16x4*)xb, stats1, N * 8);
    hipLaunchKernelGGL(fold1_kernel, dim3(225), dim3(256), 0, stream,
                       W1, gamma1, beta1, Wskip, stats1, bp1, bps, bias1,
                       feat, (int*)(outb + (size_t)N * 64),
                       1.0f / (4.0f * (float)N));
    hipLaunchKernelGGL(conv1_kernel, dim3(convBlocks), dim3(256), 0, stream,
                       xb, nbr, bp1, bias1, h, stats2, nTiles);
    hipLaunchKernelGGL(fold2_kernel, dim3(433), dim3(256), 0, stream,
                       W2, gamma2, beta2, stats2, bp2, bias2,
                       1.0f / (8.0f * (float)N));
    hipLaunchKernelGGL(conv2_kernel, dim3(convBlocks), dim3(256), 0, stream,
                       h, xb, nbr, bp2, bps, bias2, bskip, outb, nTiles);
}

// Round 10
// 1380.227 us; speedup vs baseline: 1.2006x; 1.2006x over previous
//
#include <hip/hip_runtime.h>
#include <hip/hip_bf16.h>

typedef __bf16 bf16x8 __attribute__((ext_vector_type(8)));
typedef __bf16 bf16x4 __attribute__((ext_vector_type(4)));
typedef float  f32x4  __attribute__((ext_vector_type(4)));

#define MFMA16(a, b, c) __builtin_amdgcn_mfma_f32_16x16x32_bf16((a), (b), (c), 0, 0, 0)
#define SB() __builtin_amdgcn_sched_barrier(0)

// async global->LDS copy, 16B per lane; LDS dest = wave-uniform base + lane*16
__device__ __forceinline__ void async_copy16(const void* g, void* l) {
    __builtin_amdgcn_global_load_lds(
        (const __attribute__((address_space(1))) void*)g,
        (__attribute__((address_space(3))) void*)l, 16, 0, 0);
}

// ---------------------------------------------------------------------------
__global__ void zero_stats_kernel(float* s) { s[threadIdx.x] = 0.0f; }

// ---------------------------------------------------------------------------
// Fused: GN1 stats (per-group sum/sumsq over f32 x) + cast x -> bf16 copy xb.
__global__ __launch_bounds__(256) void caststats_kernel(
    const f32x4* __restrict__ x, bf16x4* __restrict__ xb,
    float* __restrict__ stats, int nvec)
{
    int nth = gridDim.x * blockDim.x;
    int gt = blockIdx.x * blockDim.x + threadIdx.x;
    float s = 0.f, ss = 0.f;
    for (int f = gt; f < nvec; f += nth) {
        f32x4 v = x[f];
        s  += v[0] + v[1] + v[2] + v[3];
        ss += v[0] * v[0] + v[1] * v[1] + v[2] * v[2] + v[3] * v[3];
        bf16x4 b;
        b[0] = (__bf16)v[0]; b[1] = (__bf16)v[1];
        b[2] = (__bf16)v[2]; b[3] = (__bf16)v[3];
        xb[f] = b;
    }
    __shared__ float ls[16];
    if (threadIdx.x < 16) ls[threadIdx.x] = 0.f;
    __syncthreads();
    int g = gt & 7;
    atomicAdd(&ls[2 * g], s);
    atomicAdd(&ls[2 * g + 1], ss);
    __syncthreads();
    if (threadIdx.x < 16) atomicAdd(&stats[threadIdx.x], ls[threadIdx.x]);
}

// ---------------------------------------------------------------------------
// Fold GN1 affine into W1 (bf16 B-frag pack), pack Wskip, conv1 bias, feat.
// bp1 index: [k][ct][lane][j] (27*4*64*8)
__global__ __launch_bounds__(256) void fold1_kernel(
    const float* __restrict__ W1, const float* __restrict__ gamma1,
    const float* __restrict__ beta1, const float* __restrict__ Wskip,
    const float* __restrict__ stats1,
    __bf16* __restrict__ bp1, __bf16* __restrict__ bps,
    float* __restrict__ bias1,
    const int* __restrict__ feat, int* __restrict__ feat_out, float inv_n)
{
    int b = blockIdx.x, t = threadIdx.x;
    if (b < 216) {
        int e = b * 256 + t;
        int j = e & 7, lane = (e >> 3) & 63, ct = (e >> 9) & 3, k = e >> 11;
        int ci = ((lane >> 4) << 3) + j;
        int co = (ct << 4) + (lane & 15);
        int g = ci >> 2;
        float mean = stats1[2 * g] * inv_n;
        float var  = stats1[2 * g + 1] * inv_n - mean * mean;
        float r = rsqrtf(var + 1e-5f);
        float a = gamma1[ci] * r;
        bp1[e] = (__bf16)(a * W1[k * 2048 + ci * 64 + co]);
    } else if (b == 216) {
        if (t < 64) {
            float sum = 0.0f;
            for (int ci = 0; ci < 32; ++ci) {
                int g = ci >> 2;
                float mean = stats1[2 * g] * inv_n;
                float var  = stats1[2 * g + 1] * inv_n - mean * mean;
                float r = rsqrtf(var + 1e-5f);
                float a = gamma1[ci] * r;
                float bb = beta1[ci] - mean * a;
                float ws = 0.0f;
                for (int k = 0; k < 27; ++k) ws += W1[k * 2048 + ci * 64 + t];
                sum += bb * ws;
            }
            bias1[t] = sum;
        } else if (t == 64) {
            feat_out[0] = feat[0];
        }
    } else {
        int e = (b - 217) * 256 + t;
        int j = e & 7, lane = (e >> 3) & 63, ct = e >> 9;
        int ci = ((lane >> 4) << 3) + j;
        int co = (ct << 4) + (lane & 15);
        bps[e] = (__bf16)Wskip[ci * 64 + co];
    }
}

// ---------------------------------------------------------------------------
// Fold GN2 into W2.  bp2 index: [k][hf][ct][lane][j]  (27*2*4*64*8)
__global__ __launch_bounds__(256) void fold2_kernel(
    const float* __restrict__ W2, const float* __restrict__ gamma2,
    const float* __restrict__ beta2, const float* __restrict__ stats2,
    __bf16* __restrict__ bp2, float* __restrict__ bias2, float inv_n)
{
    int b = blockIdx.x, t = threadIdx.x;
    if (b < 432) {
        int e = b * 256 + t;
        int j = e & 7, lane = (e >> 3) & 63, ct = (e >> 9) & 3, hf = (e >> 11) & 1, k = e >> 12;
        int ci = (hf << 5) + ((lane >> 4) << 3) + j;
        int co = (ct << 4) + (lane & 15);
        int g = ci >> 3;
        float mean = stats2[2 * g] * inv_n;
        float var  = stats2[2 * g + 1] * inv_n - mean * mean;
        float r = rsqrtf(var + 1e-5f);
        float a = gamma2[ci] * r;
        bp2[e] = (__bf16)(a * W2[k * 4096 + ci * 64 + co]);
    } else if (t < 64) {
        float sum = 0.0f;
        for (int ci = 0; ci < 64; ++ci) {
            int g = ci >> 3;
            float mean = stats2[2 * g] * inv_n;
            float var  = stats2[2 * g + 1] * inv_n - mean * mean;
            float r = rsqrtf(var + 1e-5f);
            float a = gamma2[ci] * r;
            float bb = beta2[ci] - mean * a;
            float ws = 0.0f;
            for (int k = 0; k < 27; ++k) ws += W2[k * 4096 + ci * 64 + t];
            sum += bb * ws;
        }
        bias2[t] = sum;
    }
}

// ---------------------------------------------------------------------------
// conv1: double-buffered B (2 x 12 KB), stage issued at chunk TOP (oldest in
// vmcnt queue), rolling depth-3 gather prefetch (R4 register footprint), one
// barrier per chunk with counted vmcnt(6) -> gathers never drained.
__global__ __launch_bounds__(256, 4) void conv1_kernel(
    const __bf16* __restrict__ xb, const int* __restrict__ nbr,
    const __bf16* __restrict__ bp1, const float* __restrict__ bias1,
    __bf16* __restrict__ h, float* __restrict__ stats2, int nTiles)
{
    __shared__ int sidx[4][864];
    __shared__ __align__(16) __bf16 Bs[2][3 * 2048];   // 2 x 12 KB
    __shared__ float ls[16];
    const int wav = threadIdx.x >> 6, lane = threadIdx.x & 63;
    const int unit = blockIdx.x * 4 + wav;
    const int t0 = unit * 2;
    const bool act0 = t0 < nTiles, act1 = t0 + 1 < nTiles;
    if (threadIdx.x < 16) ls[threadIdx.x] = 0.f;
    const int lm = lane & 15, q = lane >> 4;

    {
        const int tc = act0 ? t0 : 0;
        const int* gi = nbr + (size_t)tc * 432;
        const int cnt = (act0 && act1) ? 864 : 432;
        for (int i = lane; i < 864; i += 64) sidx[wav][i] = (i < cnt) ? gi[i] : 0;
    }
    const int* s0p = &sidx[wav][lm * 27];
    const int* s1p = &sidx[wav][432 + lm * 27];
    const bf16x8* Bv0 = (const bf16x8*)Bs[0];
    const bf16x8* Bv1 = (const bf16x8*)Bs[1];

    f32x4 c[8] = {};
    bf16x8 P0[3], P1[3];                 // rolling 3-tap gather pipeline

#define STG1(CNK, BUF) { const __bf16* gs = bp1 + (size_t)(CNK) * 3 * 2048; \
    _Pragma("unroll") for (int i = 0; i < 3; ++i) { int part = wav * 3 + i; \
        async_copy16(gs + part * 512 + lane * 8, &Bs[BUF][part * 512]); } }
// tap T: gather tap T+3 (rolling), 8 MFMAs from P[T%3], then P[T%3] <- new
#define TAPG1(T, BSEL) { \
    bf16x8 n0 = {}, n1 = {}; \
    if ((T) + 3 < 27) { \
        n0 = *(const bf16x8*)(xb + (size_t)s0p[(T) + 3] * 32 + q * 8); \
        n1 = *(const bf16x8*)(xb + (size_t)s1p[(T) + 3] * 32 + q * 8); } \
    const bf16x8* Bv = (BSEL) ? Bv1 : Bv0; \
    const int bb = ((T) % 3) * 256 + lane; \
    bf16x8 b0 = Bv[bb], b1 = Bv[bb + 64], b2 = Bv[bb + 128], b3 = Bv[bb + 192]; \
    bf16x8 a0 = P0[(T) % 3], a1 = P1[(T) % 3]; \
    c[0] = MFMA16(a0, b0, c[0]); c[1] = MFMA16(a0, b1, c[1]); \
    c[2] = MFMA16(a0, b2, c[2]); c[3] = MFMA16(a0, b3, c[3]); \
    c[4] = MFMA16(a1, b0, c[4]); c[5] = MFMA16(a1, b1, c[5]); \
    c[6] = MFMA16(a1, b2, c[6]); c[7] = MFMA16(a1, b3, c[7]); \
    if ((T) + 3 < 27) { P0[(T) % 3] = n0; P1[(T) % 3] = n1; } }
// chunk C: stage C+1 FIRST (oldest), 3 taps w/ rolling gathers, counted wait
#define CHK1(C) { \
    STG1((C) + 1, ((C) + 1) & 1); SB(); \
    TAPG1(3*(C)+0, (C) & 1); \
    TAPG1(3*(C)+1, (C) & 1); \
    TAPG1(3*(C)+2, (C) & 1); \
    SB(); \
    asm volatile("s_waitcnt vmcnt(6) lgkmcnt(0)" ::: "memory"); \
    __builtin_amdgcn_s_barrier(); SB(); }

    // prologue: stage chunk0 (3 loads), gather taps 0..2 (6 loads, newer)
    STG1(0, 0); SB();
    P0[0] = *(const bf16x8*)(xb + (size_t)s0p[0] * 32 + q * 8);
    P1[0] = *(const bf16x8*)(xb + (size_t)s1p[0] * 32 + q * 8);
    P0[1] = *(const bf16x8*)(xb + (size_t)s0p[1] * 32 + q * 8);
    P1[1] = *(const bf16x8*)(xb + (size_t)s1p[1] * 32 + q * 8);
    P0[2] = *(const bf16x8*)(xb + (size_t)s0p[2] * 32 + q * 8);
    P1[2] = *(const bf16x8*)(xb + (size_t)s1p[2] * 32 + q * 8);
    SB();
    asm volatile("s_waitcnt vmcnt(6)" ::: "memory");   // stage0 retired
    __builtin_amdgcn_s_barrier(); SB();

    CHK1(0) CHK1(1) CHK1(2) CHK1(3) CHK1(4) CHK1(5) CHK1(6) CHK1(7)
    // chunk 8 (taps 24..26): compute only, no stage, no gathers
    TAPG1(24, 0) TAPG1(25, 0) TAPG1(26, 0)
#undef CHK1
#undef TAPG1
#undef STG1

    if (act0) {
        // C/D layout: col = lane&15 (cout), row = q*4 + r (voxel)
#define EPI1(CI, CT, V0) { \
        float bsv = bias1[(CT) * 16 + lm]; \
        float ps = 0.f, pss = 0.f; \
        _Pragma("unroll") \
        for (int r = 0; r < 4; ++r) { \
            float val = c[CI][r] + bsv; \
            val = val / (1.0f + __expf(-val)); \
            h[(size_t)((V0) + q * 4 + r) * 64 + (CT) * 16 + lm] = (__bf16)val; \
            ps += val; pss += val * val; } \
        int g2 = (CT) * 2 + (lm >> 3); \
        atomicAdd(&ls[2 * g2], ps); atomicAdd(&ls[2 * g2 + 1], pss); }
        const int v0 = t0 * 16;
        EPI1(0, 0, v0) EPI1(1, 1, v0) EPI1(2, 2, v0) EPI1(3, 3, v0)
        if (act1) {
            const int v1 = v0 + 16;
            EPI1(4, 0, v1) EPI1(5, 1, v1) EPI1(6, 2, v1) EPI1(7, 3, v1)
        }
#undef EPI1
    }
    __syncthreads();
    if (threadIdx.x < 16) atomicAdd(&stats2[threadIdx.x], ls[threadIdx.x]);
}

// ---------------------------------------------------------------------------
// conv2 + skip: same schedule; double-buffered B (2 x 24 KB, 2 blocks/CU),
// rolling depth-2 gather prefetch (R4 footprint), boundary vmcnt(8).
__global__ __launch_bounds__(256, 2) void conv2_kernel(
    const __bf16* __restrict__ h, const __bf16* __restrict__ xb,
    const int* __restrict__ nbr,
    const __bf16* __restrict__ bp2, const __bf16* __restrict__ bps,
    const float* __restrict__ bias2, const float* __restrict__ bskip,
    float* __restrict__ out, int nTiles)
{
    __shared__ int sidx[4][864];
    __shared__ __align__(16) __bf16 Bs[2][3 * 4096];   // 2 x 24 KB
    const int wav = threadIdx.x >> 6, lane = threadIdx.x & 63;
    const int unit = blockIdx.x * 4 + wav;
    const int t0 = unit * 2;
    const bool act0 = t0 < nTiles, act1 = t0 + 1 < nTiles;
    const int lm = lane & 15, q = lane >> 4;

    {
        const int tc = act0 ? t0 : 0;
        const int* gi = nbr + (size_t)tc * 432;
        const int cnt = (act0 && act1) ? 864 : 432;
        for (int i = lane; i < 864; i += 64) sidx[wav][i] = (i < cnt) ? gi[i] : 0;
    }
    const int* s0p = &sidx[wav][lm * 27];
    const int* s1p = &sidx[wav][432 + lm * 27];
    const bf16x8* Bv0 = (const bf16x8*)Bs[0];
    const bf16x8* Bv1 = (const bf16x8*)Bs[1];

    f32x4 c[8] = {};
    bf16x8 P0l[2], P0h[2], P1l[2], P1h[2];   // rolling 2-tap pipeline (32 VGPR)

#define STG2(CNK, BUF) { const __bf16* gs = bp2 + (size_t)(CNK) * 3 * 4096; \
    _Pragma("unroll") for (int i = 0; i < 6; ++i) { int part = wav * 6 + i; \
        async_copy16(gs + part * 512 + lane * 8, &Bs[BUF][part * 512]); } }
// tap T: gather tap T+2 (rolling), 16 MFMAs from P[T&1], then P[T&1] <- new
#define TAPG2(T, BSEL) { \
    bf16x8 n0l = {}, n0h = {}, n1l = {}, n1h = {}; \
    if ((T) + 2 < 27) { \
        const __bf16* p0 = h + (size_t)s0p[(T) + 2] * 64; \
        const __bf16* p1 = h + (size_t)s1p[(T) + 2] * 64; \
        n0l = *(const bf16x8*)(p0 + q * 8); \
        n0h = *(const bf16x8*)(p0 + 32 + q * 8); \
        n1l = *(const bf16x8*)(p1 + q * 8); \
        n1h = *(const bf16x8*)(p1 + 32 + q * 8); } \
    const bf16x8* Bv = (BSEL) ? Bv1 : Bv0; \
    const int bb = ((T) % 3) * 512 + lane; \
    bf16x8 a0l = P0l[(T) & 1], a0h = P0h[(T) & 1]; \
    bf16x8 a1l = P1l[(T) & 1], a1h = P1h[(T) & 1]; \
    bf16x8 b0 = Bv[bb], b1 = Bv[bb + 64], b2 = Bv[bb + 128], b3 = Bv[bb + 192]; \
    c[0] = MFMA16(a0l, b0, c[0]); c[1] = MFMA16(a0l, b1, c[1]); \
    c[2] = MFMA16(a0l, b2, c[2]); c[3] = MFMA16(a0l, b3, c[3]); \
    c[4] = MFMA16(a1l, b0, c[4]); c[5] = MFMA16(a1l, b1, c[5]); \
    c[6] = MFMA16(a1l, b2, c[6]); c[7] = MFMA16(a1l, b3, c[7]); \
    bf16x8 b4 = Bv[bb + 256], b5 = Bv[bb + 320], b6 = Bv[bb + 384], b7 = Bv[bb + 448]; \
    c[0] = MFMA16(a0h, b4, c[0]); c[1] = MFMA16(a0h, b5, c[1]); \
    c[2] = MFMA16(a0h, b6, c[2]); c[3] = MFMA16(a0h, b7, c[3]); \
    c[4] = MFMA16(a1h, b4, c[4]); c[5] = MFMA16(a1h, b5, c[5]); \
    c[6] = MFMA16(a1h, b6, c[6]); c[7] = MFMA16(a1h, b7, c[7]); \
    if ((T) + 2 < 27) { P0l[(T) & 1] = n0l; P0h[(T) & 1] = n0h; \
                        P1l[(T) & 1] = n1l; P1h[(T) & 1] = n1h; } }
#define CHK2(C) { \
    STG2((C) + 1, ((C) + 1) & 1); SB(); \
    TAPG2(3*(C)+0, (C) & 1); \
    TAPG2(3*(C)+1, (C) & 1); \
    TAPG2(3*(C)+2, (C) & 1); \
    SB(); \
    asm volatile("s_waitcnt vmcnt(8) lgkmcnt(0)" ::: "memory"); \
    __builtin_amdgcn_s_barrier(); SB(); }

    // prologue: stage chunk0 (6 loads), gather taps 0..1 (8 loads, newer)
    STG2(0, 0); SB();
    {
        const __bf16* p0 = h + (size_t)s0p[0] * 64;
        const __bf16* p1 = h + (size_t)s1p[0] * 64;
        P0l[0] = *(const bf16x8*)(p0 + q * 8);
        P0h[0] = *(const bf16x8*)(p0 + 32 + q * 8);
        P1l[0] = *(const bf16x8*)(p1 + q * 8);
        P1h[0] = *(const bf16x8*)(p1 + 32 + q * 8);
        const __bf16* r0 = h + (size_t)s0p[1] * 64;
        const __bf16* r1 = h + (size_t)s1p[1] * 64;
        P0l[1] = *(const bf16x8*)(r0 + q * 8);
        P0h[1] = *(const bf16x8*)(r0 + 32 + q * 8);
        P1l[1] = *(const bf16x8*)(r1 + q * 8);
        P1h[1] = *(const bf16x8*)(r1 + 32 + q * 8);
    }
    SB();
    asm volatile("s_waitcnt vmcnt(8)" ::: "memory");   // stage0 retired
    __builtin_amdgcn_s_barrier(); SB();

    CHK2(0) CHK2(1) CHK2(2) CHK2(3) CHK2(4) CHK2(5) CHK2(6) CHK2(7)
    // chunk 8 (taps 24..26): compute only
    TAPG2(24, 0) TAPG2(25, 0) TAPG2(26, 0)
#undef CHK2
#undef TAPG2
#undef STG2

    if (!act0) return;
    // skip 1x1 conv after the K-loop (short accumulator live range)
    f32x4 s[8] = {};
    {
        const bf16x8* bsp = (const bf16x8*)bps;
        bf16x8 ax0 = *(const bf16x8*)(xb + ((size_t)t0 * 16 + lm) * 32 + q * 8);
        bf16x8 w0 = bsp[lane], w1 = bsp[64 + lane], w2 = bsp[128 + lane], w3 = bsp[192 + lane];
        s[0] = MFMA16(ax0, w0, s[0]);
        s[1] = MFMA16(ax0, w1, s[1]);
        s[2] = MFMA16(ax0, w2, s[2]);
        s[3] = MFMA16(ax0, w3, s[3]);
        if (act1) {
            bf16x8 ax1 = *(const bf16x8*)(xb + ((size_t)t0 * 16 + 16 + lm) * 32 + q * 8);
            s[4] = MFMA16(ax1, w0, s[4]);
            s[5] = MFMA16(ax1, w1, s[5]);
            s[6] = MFMA16(ax1, w2, s[6]);
            s[7] = MFMA16(ax1, w3, s[7]);
        }
    }
#define EPI2(CI, CT, V0) { \
        int co = (CT) * 16 + lm; \
        float b2v = bias2[co]; \
        float bsk = bskip[co]; \
        _Pragma("unroll") \
        for (int r = 0; r < 4; ++r) { \
            float val = c[CI][r] + b2v; \
            val = val / (1.0f + __expf(-val)); \
            val += s[CI][r] + bsk; \
            out[(size_t)((V0) + q * 4 + r) * 64 + co] = val; } }
    const int v0 = t0 * 16;
    EPI2(0, 0, v0) EPI2(1, 1, v0) EPI2(2, 2, v0) EPI2(3, 3, v0)
    if (act1) {
        const int v1 = v0 + 16;
        EPI2(4, 0, v1) EPI2(5, 1, v1) EPI2(6, 2, v1) EPI2(7, 3, v1)
    }
#undef EPI2
}

// ---------------------------------------------------------------------------
extern "C" void kernel_launch(void* const* d_in, const int* in_sizes, int n_in,
                              void* d_out, int out_size, void* d_ws, size_t ws_size,
                              hipStream_t stream)
{
    (void)n_in; (void)out_size; (void)ws_size;
    const float* x      = (const float*)d_in[0];
    const int*   nbr    = (const int*)d_in[1];
    const float* gamma1 = (const float*)d_in[2];
    const float* beta1  = (const float*)d_in[3];
    const float* W1     = (const float*)d_in[4];
    const float* gamma2 = (const float*)d_in[5];
    const float* beta2  = (const float*)d_in[6];
    const float* W2     = (const float*)d_in[7];
    const float* Wskip  = (const float*)d_in[8];
    const float* bskip  = (const float*)d_in[9];
    const int*   feat   = (const int*)d_in[10];
    const int N = in_sizes[0] / 32;

    char* ws = (char*)d_ws;
    float* stats1 = (float*)ws;                 // 16 floats
    float* stats2 = stats1 + 16;                // 16 floats
    float* bias1  = stats1 + 32;                // 64 floats
    float* bias2  = stats1 + 96;                // 64 floats
    __bf16* bp1 = (__bf16*)(ws + (1 << 10));    // 55296 elems
    __bf16* bps = (__bf16*)(ws + (1 << 17));    // 2048 elems
    __bf16* bp2 = (__bf16*)(ws + 144 * 1024);   // 110592 elems
    __bf16* xb  = (__bf16*)(ws + (1 << 20));    // N*32 bf16 = 32 MB
    __bf16* h   = (__bf16*)(ws + (size_t)34 * (1 << 20)); // N*64 bf16 = 64 MB
    float* outb = (float*)d_out;

    const int nTiles = (N + 15) / 16;           // 31250
    const int units = (nTiles + 1) / 2;         // 15625
    const int convBlocks = (units + 3) / 4;     // 3907

    hipLaunchKernelGGL(zero_stats_kernel, dim3(1), dim3(32), 0, stream, stats1);
    hipLaunchKernelGGL(caststats_kernel, dim3(2048), dim3(256), 0, stream,
                       (const f32x4*)x, (bf16x4*)xb, stats1, N * 8);
    hipLaunchKernelGGL(fold1_kernel, dim3(225), dim3(256), 0, stream,
                       W1, gamma1, beta1, Wskip, stats1, bp1, bps, bias1,
                       feat, (int*)(outb + (size_t)N * 64),
                       1.0f / (4.0f * (float)N));
    hipLaunchKernelGGL(conv1_kernel, dim3(convBlocks), dim3(256), 0, stream,
                       xb, nbr, bp1, bias1, h, stats2, nTiles);
    hipLaunchKernelGGL(fold2_kernel, dim3(433), dim3(256), 0, stream,
                       W2, gamma2, beta2, stats2, bp2, bias2,
                       1.0f / (8.0f * (float)N));
    hipLaunchKernelGGL(conv2_kernel, dim3(convBlocks), dim3(256), 0, stream,
                       h, xb, nbr, bp2, bps, bias2, bskip, outb, nTiles);
}

// Round 15
// 814.746 us; speedup vs baseline: 2.0339x; 1.6941x over previous
//
#include <hip/hip_runtime.h>
#include <hip/hip_bf16.h>

typedef __bf16 bf16x8 __attribute__((ext_vector_type(8)));
typedef __bf16 bf16x4 __attribute__((ext_vector_type(4)));
typedef float  f32x4  __attribute__((ext_vector_type(4)));

#define MFMA16(a, b, c) __builtin_amdgcn_mfma_f32_16x16x32_bf16((a), (b), (c), 0, 0, 0)

// async global->LDS copy, 16B per lane; LDS dest = wave-uniform base + lane*16
__device__ __forceinline__ void async_copy16(const void* g, void* l) {
    __builtin_amdgcn_global_load_lds(
        (const __attribute__((address_space(1))) void*)g,
        (__attribute__((address_space(3))) void*)l, 16, 0, 0);
}

// ---------------------------------------------------------------------------
__global__ void zero_stats_kernel(float* s) { s[threadIdx.x] = 0.0f; }

// ---------------------------------------------------------------------------
// Fused: GN1 stats (per-group sum/sumsq over f32 x) + cast x -> bf16 copy xb.
__global__ __launch_bounds__(256) void caststats_kernel(
    const f32x4* __restrict__ x, bf16x4* __restrict__ xb,
    float* __restrict__ stats, int nvec)
{
    int nth = gridDim.x * blockDim.x;
    int gt = blockIdx.x * blockDim.x + threadIdx.x;
    float s = 0.f, ss = 0.f;
    for (int f = gt; f < nvec; f += nth) {
        f32x4 v = x[f];
        s  += v[0] + v[1] + v[2] + v[3];
        ss += v[0] * v[0] + v[1] * v[1] + v[2] * v[2] + v[3] * v[3];
        bf16x4 b;
        b[0] = (__bf16)v[0]; b[1] = (__bf16)v[1];
        b[2] = (__bf16)v[2]; b[3] = (__bf16)v[3];
        xb[f] = b;
    }
    __shared__ float ls[16];
    if (threadIdx.x < 16) ls[threadIdx.x] = 0.f;
    __syncthreads();
    int g = gt & 7;
    atomicAdd(&ls[2 * g], s);
    atomicAdd(&ls[2 * g + 1], ss);
    __syncthreads();
    if (threadIdx.x < 16) atomicAdd(&stats[threadIdx.x], ls[threadIdx.x]);
}

// ---------------------------------------------------------------------------
// Fold GN1 affine into W1 (bf16 B-frag pack), pack Wskip, conv1 bias, feat.
// bp1 index: [k][ct][lane][j] (27*4*64*8)
__global__ __launch_bounds__(256) void fold1_kernel(
    const float* __restrict__ W1, const float* __restrict__ gamma1,
    const float* __restrict__ beta1, const float* __restrict__ Wskip,
    const float* __restrict__ stats1,
    __bf16* __restrict__ bp1, __bf16* __restrict__ bps,
    float* __restrict__ bias1,
    const int* __restrict__ feat, int* __restrict__ feat_out, float inv_n)
{
    int b = blockIdx.x, t = threadIdx.x;
    if (b < 216) {
        int e = b * 256 + t;
        int j = e & 7, lane = (e >> 3) & 63, ct = (e >> 9) & 3, k = e >> 11;
        int ci = ((lane >> 4) << 3) + j;
        int co = (ct << 4) + (lane & 15);
        int g = ci >> 2;
        float mean = stats1[2 * g] * inv_n;
        float var  = stats1[2 * g + 1] * inv_n - mean * mean;
        float r = rsqrtf(var + 1e-5f);
        float a = gamma1[ci] * r;
        bp1[e] = (__bf16)(a * W1[k * 2048 + ci * 64 + co]);
    } else if (b == 216) {
        if (t < 64) {
            float sum = 0.0f;
            for (int ci = 0; ci < 32; ++ci) {
                int g = ci >> 2;
                float mean = stats1[2 * g] * inv_n;
                float var  = stats1[2 * g + 1] * inv_n - mean * mean;
                float r = rsqrtf(var + 1e-5f);
                float a = gamma1[ci] * r;
                float bb = beta1[ci] - mean * a;
                float ws = 0.0f;
                for (int k = 0; k < 27; ++k) ws += W1[k * 2048 + ci * 64 + t];
                sum += bb * ws;
            }
            bias1[t] = sum;
        } else if (t == 64) {
            feat_out[0] = feat[0];
        }
    } else {
        int e = (b - 217) * 256 + t;
        int j = e & 7, lane = (e >> 3) & 63, ct = e >> 9;
        int ci = ((lane >> 4) << 3) + j;
        int co = (ct << 4) + (lane & 15);
        bps[e] = (__bf16)Wskip[ci * 64 + co];
    }
}

// ---------------------------------------------------------------------------
// Fold GN2 into W2.  bp2 index: [k][hf][ct][lane][j]  (27*2*4*64*8)
__global__ __launch_bounds__(256) void fold2_kernel(
    const float* __restrict__ W2, const float* __restrict__ gamma2,
    const float* __restrict__ beta2, const float* __restrict__ stats2,
    __bf16* __restrict__ bp2, float* __restrict__ bias2, float inv_n)
{
    int b = blockIdx.x, t = threadIdx.x;
    if (b < 432) {
        int e = b * 256 + t;
        int j = e & 7, lane = (e >> 3) & 63, ct = (e >> 9) & 3, hf = (e >> 11) & 1, k = e >> 12;
        int ci = (hf << 5) + ((lane >> 4) << 3) + j;
        int co = (ct << 4) + (lane & 15);
        int g = ci >> 3;
        float mean = stats2[2 * g] * inv_n;
        float var  = stats2[2 * g + 1] * inv_n - mean * mean;
        float r = rsqrtf(var + 1e-5f);
        float a = gamma2[ci] * r;
        bp2[e] = (__bf16)(a * W2[k * 4096 + ci * 64 + co]);
    } else if (t < 64) {
        float sum = 0.0f;
        for (int ci = 0; ci < 64; ++ci) {
            int g = ci >> 3;
            float mean = stats2[2 * g] * inv_n;
            float var  = stats2[2 * g + 1] * inv_n - mean * mean;
            float r = rsqrtf(var + 1e-5f);
            float a = gamma2[ci] * r;
            float bb = beta2[ci] - mean * a;
            float ws = 0.0f;
            for (int k = 0; k < 27; ++k) ws += W2[k * 4096 + ci * 64 + t];
            sum += bb * ws;
        }
        bias2[t] = sum;
    }
}

// ---------------------------------------------------------------------------
// conv1: R4 structure (B staged in LDS, 3-tap chunks, compiler-managed
// schedule) with sidx removed: neighbor indices read via per-lane global
// pointers (108 B/lane, L1-resident). LDS 12.4 KB -> ~7 blocks/CU.
__global__ __launch_bounds__(256, 4) void conv1_kernel(
    const __bf16* __restrict__ xb, const int* __restrict__ nbr,
    const __bf16* __restrict__ bp1, const float* __restrict__ bias1,
    __bf16* __restrict__ h, float* __restrict__ stats2, int nTiles)
{
    __shared__ __align__(16) __bf16 Bs[3 * 2048];   // 3 taps x 4 KB = 12 KB
    __shared__ float ls[16];
    const int wav = threadIdx.x >> 6, lane = threadIdx.x & 63;
    const int unit = blockIdx.x * 4 + wav;
    const int t0 = unit * 2;
    const bool act0 = t0 < nTiles, act1 = t0 + 1 < nTiles;
    if (threadIdx.x < 16) ls[threadIdx.x] = 0.f;
    const int lm = lane & 15, q = lane >> 4;
    // per-lane index pointers (inactive waves clamp to voxel lm: in-bounds)
    const int* ip0 = nbr + (size_t)(act0 ? t0 * 16 + lm : lm) * 27;
    const int* ip1 = nbr + (size_t)(act1 ? t0 * 16 + 16 + lm : lm) * 27;

    // stage B chunk 0 (taps 0..2): 12 wave-calls of 1 KB
#pragma unroll
    for (int i = 0; i < 3; ++i) {
        int part = wav * 3 + i;                      // 0..11
        async_copy16(bp1 + (size_t)part * 512 + lane * 8, &Bs[part * 512]);
    }

    f32x4 c[8] = {};
    bf16x8 P0[3], P1[3];                             // depth-3 gather pipeline
#pragma unroll
    for (int k = 0; k < 3; ++k) {
        P0[k] = *(const bf16x8*)(xb + (size_t)ip0[k] * 32 + q * 8);
        P1[k] = *(const bf16x8*)(xb + (size_t)ip1[k] * 32 + q * 8);
    }
    __syncthreads();                                 // Bs chunk 0 visible

    const bf16x8* Bv = (const bf16x8*)Bs;
#pragma unroll
    for (int k = 0; k < 27; ++k) {
        const int sl = k % 3;
        bf16x8 n0, n1;
        if (k + 3 < 27) {
            n0 = *(const bf16x8*)(xb + (size_t)ip0[k + 3] * 32 + q * 8);
            n1 = *(const bf16x8*)(xb + (size_t)ip1[k + 3] * 32 + q * 8);
        }
        const int bb = sl * 256 + lane;
        bf16x8 b0 = Bv[bb], b1 = Bv[bb + 64], b2 = Bv[bb + 128], b3 = Bv[bb + 192];
        bf16x8 a0 = P0[sl], a1 = P1[sl];
        c[0] = MFMA16(a0, b0, c[0]);
        c[1] = MFMA16(a0, b1, c[1]);
        c[2] = MFMA16(a0, b2, c[2]);
        c[3] = MFMA16(a0, b3, c[3]);
        c[4] = MFMA16(a1, b0, c[4]);
        c[5] = MFMA16(a1, b1, c[5]);
        c[6] = MFMA16(a1, b2, c[6]);
        c[7] = MFMA16(a1, b3, c[7]);
        if (k + 3 < 27) { P0[sl] = n0; P1[sl] = n1; }
        if ((k % 3) == 2 && k < 26) {
            __syncthreads();                         // all waves done with chunk
            const __bf16* gsrc = bp1 + (size_t)(k / 3 + 1) * 3 * 2048;
#pragma unroll
            for (int i = 0; i < 3; ++i) {
                int part = wav * 3 + i;
                async_copy16(gsrc + (size_t)part * 512 + lane * 8, &Bs[part * 512]);
            }
            __syncthreads();                         // next chunk staged
        }
    }

    if (act0) {
        // C/D layout: col = lane&15 (cout), row = q*4 + r (voxel)
#define EPI1(CI, CT, V0) { \
        float bsv = bias1[(CT) * 16 + lm]; \
        float ps = 0.f, pss = 0.f; \
        _Pragma("unroll") \
        for (int r = 0; r < 4; ++r) { \
            float val = c[CI][r] + bsv; \
            val = val / (1.0f + __expf(-val)); \
            h[(size_t)((V0) + q * 4 + r) * 64 + (CT) * 16 + lm] = (__bf16)val; \
            ps += val; pss += val * val; } \
        int g2 = (CT) * 2 + (lm >> 3); \
        atomicAdd(&ls[2 * g2], ps); atomicAdd(&ls[2 * g2 + 1], pss); }
        const int v0 = t0 * 16;
        EPI1(0, 0, v0) EPI1(1, 1, v0) EPI1(2, 2, v0) EPI1(3, 3, v0)
        if (act1) {
            const int v1 = v0 + 16;
            EPI1(4, 0, v1) EPI1(5, 1, v1) EPI1(6, 2, v1) EPI1(7, 3, v1)
        }
#undef EPI1
    }
    __syncthreads();
    if (threadIdx.x < 16) atomicAdd(&stats2[threadIdx.x], ls[threadIdx.x]);
}

// ---------------------------------------------------------------------------
// conv2 + skip: R4 structure, sidx removed (global idx pointers). LDS
// 24.6 KB -> 6 blocks/CU (24 waves, was 4 blocks/16 waves with sidx).
__global__ __launch_bounds__(256, 4) void conv2_kernel(
    const __bf16* __restrict__ h, const __bf16* __restrict__ xb,
    const int* __restrict__ nbr,
    const __bf16* __restrict__ bp2, const __bf16* __restrict__ bps,
    const float* __restrict__ bias2, const float* __restrict__ bskip,
    float* __restrict__ out, int nTiles)
{
    __shared__ __align__(16) __bf16 Bs[3 * 4096];   // 3 taps x 8 KB = 24 KB
    const int wav = threadIdx.x >> 6, lane = threadIdx.x & 63;
    const int unit = blockIdx.x * 4 + wav;
    const int t0 = unit * 2;
    const bool act0 = t0 < nTiles, act1 = t0 + 1 < nTiles;
    const int lm = lane & 15, q = lane >> 4;
    const int* ip0 = nbr + (size_t)(act0 ? t0 * 16 + lm : lm) * 27;
    const int* ip1 = nbr + (size_t)(act1 ? t0 * 16 + 16 + lm : lm) * 27;

    // stage B chunk 0 (taps 0..2): 24 wave-calls of 1 KB
#pragma unroll
    for (int i = 0; i < 6; ++i) {
        int part = wav * 6 + i;                      // 0..23
        async_copy16(bp2 + (size_t)part * 512 + lane * 8, &Bs[part * 512]);
    }

    f32x4 c[8] = {};
    bf16x8 P0l[2], P0h[2], P1l[2], P1h[2];           // depth-2 gather pipeline
#pragma unroll
    for (int k = 0; k < 2; ++k) {
        const __bf16* r0 = h + (size_t)ip0[k] * 64;
        const __bf16* r1 = h + (size_t)ip1[k] * 64;
        P0l[k] = *(const bf16x8*)(r0 + q * 8);
        P0h[k] = *(const bf16x8*)(r0 + 32 + q * 8);
        P1l[k] = *(const bf16x8*)(r1 + q * 8);
        P1h[k] = *(const bf16x8*)(r1 + 32 + q * 8);
    }
    __syncthreads();                                 // Bs chunk 0 visible

    const bf16x8* Bv = (const bf16x8*)Bs;
#pragma unroll
    for (int k = 0; k < 27; ++k) {
        const int sl = k & 1;
        bf16x8 n0l, n0h, n1l, n1h;
        if (k + 2 < 27) {
            const __bf16* p0 = h + (size_t)ip0[k + 2] * 64;
            const __bf16* p1 = h + (size_t)ip1[k + 2] * 64;
            n0l = *(const bf16x8*)(p0 + q * 8);
            n0h = *(const bf16x8*)(p0 + 32 + q * 8);
            n1l = *(const bf16x8*)(p1 + q * 8);
            n1h = *(const bf16x8*)(p1 + 32 + q * 8);
        }
        const int bb = (k % 3) * 512 + lane;
        bf16x8 b0 = Bv[bb],       b1 = Bv[bb + 64];
        bf16x8 b2 = Bv[bb + 128], b3 = Bv[bb + 192];
        bf16x8 a0l = P0l[sl], a0h = P0h[sl], a1l = P1l[sl], a1h = P1h[sl];
        c[0] = MFMA16(a0l, b0, c[0]);
        c[1] = MFMA16(a0l, b1, c[1]);
        c[2] = MFMA16(a0l, b2, c[2]);
        c[3] = MFMA16(a0l, b3, c[3]);
        c[4] = MFMA16(a1l, b0, c[4]);
        c[5] = MFMA16(a1l, b1, c[5]);
        c[6] = MFMA16(a1l, b2, c[6]);
        c[7] = MFMA16(a1l, b3, c[7]);
        bf16x8 b4 = Bv[bb + 256], b5 = Bv[bb + 320];
        bf16x8 b6 = Bv[bb + 384], b7 = Bv[bb + 448];
        c[0] = MFMA16(a0h, b4, c[0]);
        c[1] = MFMA16(a0h, b5, c[1]);
        c[2] = MFMA16(a0h, b6, c[2]);
        c[3] = MFMA16(a0h, b7, c[3]);
        c[4] = MFMA16(a1h, b4, c[4]);
        c[5] = MFMA16(a1h, b5, c[5]);
        c[6] = MFMA16(a1h, b6, c[6]);
        c[7] = MFMA16(a1h, b7, c[7]);
        if (k + 2 < 27) { P0l[sl] = n0l; P0h[sl] = n0h; P1l[sl] = n1l; P1h[sl] = n1h; }
        if ((k % 3) == 2 && k < 26) {
            __syncthreads();                         // all waves done with chunk
            const __bf16* gsrc = bp2 + (size_t)(k / 3 + 1) * 3 * 4096;
#pragma unroll
            for (int i = 0; i < 6; ++i) {
                int part = wav * 6 + i;
                async_copy16(gsrc + (size_t)part * 512 + lane * 8, &Bs[part * 512]);
            }
            __syncthreads();                         // next chunk staged
        }
    }

    if (!act0) return;
    // skip 1x1 conv after the K-loop (short accumulator live range)
    f32x4 s[8] = {};
    {
        const bf16x8* bsp = (const bf16x8*)bps;
        bf16x8 ax0 = *(const bf16x8*)(xb + ((size_t)t0 * 16 + lm) * 32 + q * 8);
        bf16x8 w0 = bsp[lane], w1 = bsp[64 + lane], w2 = bsp[128 + lane], w3 = bsp[192 + lane];
        s[0] = MFMA16(ax0, w0, s[0]);
        s[1] = MFMA16(ax0, w1, s[1]);
        s[2] = MFMA16(ax0, w2, s[2]);
        s[3] = MFMA16(ax0, w3, s[3]);
        if (act1) {
            bf16x8 ax1 = *(const bf16x8*)(xb + ((size_t)t0 * 16 + 16 + lm) * 32 + q * 8);
            s[4] = MFMA16(ax1, w0, s[4]);
            s[5] = MFMA16(ax1, w1, s[5]);
            s[6] = MFMA16(ax1, w2, s[6]);
            s[7] = MFMA16(ax1, w3, s[7]);
        }
    }
#define EPI2(CI, CT, V0) { \
        int co = (CT) * 16 + lm; \
        float b2v = bias2[co]; \
        float bsk = bskip[co]; \
        _Pragma("unroll") \
        for (int r = 0; r < 4; ++r) { \
            float val = c[CI][r] + b2v; \
            val = val / (1.0f + __expf(-val)); \
            val += s[CI][r] + bsk; \
            out[(size_t)((V0) + q * 4 + r) * 64 + co] = val; } }
    const int v0 = t0 * 16;
    EPI2(0, 0, v0) EPI2(1, 1, v0) EPI2(2, 2, v0) EPI2(3, 3, v0)
    if (act1) {
        const int v1 = v0 + 16;
        EPI2(4, 0, v1) EPI2(5, 1, v1) EPI2(6, 2, v1) EPI2(7, 3, v1)
    }
#undef EPI2
}

// ---------------------------------------------------------------------------
extern "C" void kernel_launch(void* const* d_in, const int* in_sizes, int n_in,
                              void* d_out, int out_size, void* d_ws, size_t ws_size,
                              hipStream_t stream)
{
    (void)n_in; (void)out_size; (void)ws_size;
    const float* x      = (const float*)d_in[0];
    const int*   nbr    = (const int*)d_in[1];
    const float* gamma1 = (const float*)d_in[2];
    const float* beta1  = (const float*)d_in[3];
    const float* W1     = (const float*)d_in[4];
    const float* gamma2 = (const float*)d_in[5];
    const float* beta2  = (const float*)d_in[6];
    const float* W2     = (const float*)d_in[7];
    const float* Wskip  = (const float*)d_in[8];
    const float* bskip  = (const float*)d_in[9];
    const int*   feat   = (const int*)d_in[10];
    const int N = in_sizes[0] / 32;

    char* ws = (char*)d_ws;
    float* stats1 = (float*)ws;                 // 16 floats
    float* stats2 = stats1 + 16;                // 16 floats
    float* bias1  = stats1 + 32;                // 64 floats
    float* bias2  = stats1 + 96;                // 64 floats
    __bf16* bp1 = (__bf16*)(ws + (1 << 10));    // 55296 elems
    __bf16* bps = (__bf16*)(ws + (1 << 17));    // 2048 elems
    __bf16* bp2 = (__bf16*)(ws + 144 * 1024);   // 110592 elems
    __bf16* xb  = (__bf16*)(ws + (1 << 20));    // N*32 bf16 = 32 MB
    __bf16* h   = (__bf16*)(ws + (size_t)34 * (1 << 20)); // N*64 bf16 = 64 MB
    float* outb = (float*)d_out;

    const int nTiles = (N + 15) / 16;           // 31250
    const int units = (nTiles + 1) / 2;         // 15625
    const int convBlocks = (units + 3) / 4;     // 3907

    hipLaunchKernelGGL(zero_stats_kernel, dim3(1), dim3(32), 0, stream, stats1);
    hipLaunchKernelGGL(caststats_kernel, dim3(2048), dim3(256), 0, stream,
                       (const f32x4*)x, (bf16x4*)xb, stats1, N * 8);
    hipLaunchKernelGGL(fold1_kernel, dim3(225), dim3(256), 0, stream,
                       W1, gamma1, beta1, Wskip, stats1, bp1, bps, bias1,
                       feat, (int*)(outb + (size_t)N * 64),
                       1.0f / (4.0f * (float)N));
    hipLaunchKernelGGL(conv1_kernel, dim3(convBlocks), dim3(256), 0, stream,
                       xb, nbr, bp1, bias1, h, stats2, nTiles);
    hipLaunchKernelGGL(fold2_kernel, dim3(433), dim3(256), 0, stream,
                       W2, gamma2, beta2, stats2, bp2, bias2,
                       1.0f / (8.0f * (float)N));
    hipLaunchKernelGGL(conv2_kernel, dim3(convBlocks), dim3(256), 0, stream,
                       h, xb, nbr, bp2, bps, bias2, bskip, outb, nTiles);
}